// Round 14
// baseline (81.838 us; speedup 1.0000x reference)
//
#include <hip/hip_runtime.h>
#include <hip/hip_bf16.h>

// Problem constants (match reference)
#define BATCH   8
#define CDIM    256
#define ODIM    16
#define GRID16  16
#define NCELL   4096            // 16*16*16
#define PADW    17
#define PADV    (PADW*PADW*PADW)
#define MAXK    32              // point chunks per batch (256 blocks total)
#define SENT16  0x007Fu         // mapped bf16 -inf
#define SENTPK  0x007F007Fu
#define TPB     1024            // 16 waves = 4/SIMD: cap 128 regs >= 84 live (R13)
#define NT      4               // M-tiles (16 pts each) per wave-iteration

// ws layout (u32 words):
//   [0, 1024)      : W1b1 packed float4 per c  (w1x,w1y,w1z,b1)
//   [1024, 3072)   : W2 bf16 MFMA A-fragments, uint4 per (kt*64+lane)
//                    lane l supplies A[m=och=l&15][k=(l>>4)*8+j],
//                    k-map: c(kt,j,g) = kt*32 + (j>>2)*16 + 4g + (j&3)
//   [4096, ...)    : Km * BATCH slabs of 4096*8 packed-bf16-pair u32
//                    word index = cell*8 + op   (op = channel pair 0..7)
#define HDR_WORDS   4096
#define SLAB_WORDS  (8 * 4096)   // 32768 u32 = 128 KiB

typedef __attribute__((ext_vector_type(8))) short bf16x8;
typedef __attribute__((ext_vector_type(4))) float f32x4;
typedef __attribute__((ext_vector_type(4))) unsigned u32x4;

// ---------------------------------------------------------------------------
__device__ __forceinline__ float unmap16(unsigned m) {
    unsigned r = (m & 0x8000u) ? (m ^ 0x8000u) : (~m & 0xFFFFu);
    return __uint_as_float(r << 16);
}
// packed pair map: per 16-bit field, r ^= (sign ? 0xFFFF : 0x8000)
__device__ __forceinline__ unsigned mpk(unsigned w) {
    return w ^ (0x80008000u | (((w >> 15) & 0x00010001u) * 0x7FFFu));
}
// two fp32 -> packed bf16 pair (lo = first): single HW instruction (T12)
__device__ __forceinline__ unsigned pkbf16(float lo, float hi) {
    unsigned r;
    asm("v_cvt_pk_bf16_f32 %0, %1, %2" : "=v"(r) : "v"(lo), "v"(hi));
    return r;
}
// packed-pair unsigned max per 16-bit field
__device__ __forceinline__ unsigned pmax(unsigned a, unsigned b) {
    unsigned hi = max(a >> 16, b >> 16);
    unsigned lo = max(a & 0xFFFFu, b & 0xFFFFu);
    return (hi << 16) | lo;
}

// ---------------------------------------------------------------------------
__global__ void k_pack2(const float* __restrict__ W1, const float* __restrict__ b1,
                        const float* __restrict__ W2, unsigned* __restrict__ ws) {
    int t = threadIdx.x;                    // 512 threads
    float* w1p = reinterpret_cast<float*>(ws);
    if (t < 256) {
        float4 v;
        v.x = W1[t * 3 + 0];
        v.y = W1[t * 3 + 1];
        v.z = W1[t * 3 + 2];
        v.w = b1[t];
        reinterpret_cast<float4*>(w1p)[t] = v;
    }
    // W2 A fragments, k-map c(kt,j,g) = kt*32 + (j>>2)*16 + 4g + (j&3)
    int kt = t >> 6, l = t & 63;
    int g = (l >> 4), o = l & 15;
    const float* wr = W2 + o * CDIM + kt * 32 + 4 * g;   // base
    uint4 q;
    q.x = pkbf16(wr[0],  wr[1]);
    q.y = pkbf16(wr[2],  wr[3]);
    q.z = pkbf16(wr[16], wr[17]);
    q.w = pkbf16(wr[18], wr[19]);
    reinterpret_cast<uint4*>(ws + 1024)[t] = q;
}

// ---------------------------------------------------------------------------
__device__ __forceinline__ void casmax(unsigned* addr, unsigned wv) {
    unsigned cur = *addr;
    while (true) {
        unsigned nv = pmax(cur, wv);
        if (nv == cur) return;
        unsigned prev = atomicCAS(addr, cur, nv);
        if (prev == cur) return;
        cur = prev;
    }
}

__device__ __forceinline__ bf16x8 mk_frag(unsigned w0, unsigned w1) {
    u32x4 u = {w0, w1, 0u, 0u};
    return __builtin_bit_cast(bf16x8, u);
}

// ---------------------------------------------------------------------------
// MFMA scatter: block (k, b). 16 waves (4/SIMD); NT=4 16-point M-tiles per
// wave-iteration. Both layers on MFMA, fragments in VGPRs.
//   L1: h[ch16][pt16]  = W1(A) * x(B)            [K=4 of 32 used]
//   L2: D[och16][pt16] = W2(A) * h(B) + b2(C-in) [operand-swapped]
// R13: TLP 2->3 waves/SIMD gave +7%; live set is 84 regs so 4 waves/SIMD
// (cap 512/4 = 128) now fits -- the config R6 couldn't use at ~200 live regs.
__global__ __launch_bounds__(TPB, 1)
void k_scatter_mfma(const float* __restrict__ xin,
                    const unsigned* __restrict__ ws,
                    const float* __restrict__ b2,
                    unsigned* __restrict__ slabs,
                    int nper, int chunk) {
    __shared__ unsigned cm[SLAB_WORDS];      // 128 KiB
    const int kblk = blockIdx.x, b = blockIdx.z;
    const int tid = threadIdx.x;
    const int l = tid & 63, wv = tid >> 6;   // lane, wave (0..15)
    const int g = l >> 4;                    // lane group 0..3
    const bool g0 = (g == 0);
    const int lp = l & 15;                   // point slot within tile

    {   // vectorized sentinel init: 8192 uint4
        u32x4 s = {SENTPK, SENTPK, SENTPK, SENTPK};
        u32x4* cm4 = reinterpret_cast<u32x4*>(cm);
        for (int i = tid; i < SLAB_WORDS / 4; i += TPB) cm4[i] = s;
    }

    // ---- W1 A-fragments (16 channel groups) into registers ----
    bf16x8 w1f[16];
    {
        const float4* w1p = reinterpret_cast<const float4*>(ws);
#pragma unroll
        for (int cg = 0; cg < 16; ++cg) {
            float4 w = w1p[cg * 16 + lp];
            unsigned a0 = g0 ? pkbf16(w.x, w.y) : 0u;
            unsigned a1 = g0 ? pkbf16(w.z, w.w) : 0u;
            w1f[cg] = mk_frag(a0, a1);
        }
    }
    // ---- W2 A-fragments into registers ----
    bf16x8 w2f[8];
#pragma unroll
    for (int kt = 0; kt < 8; ++kt) {
        u32x4 q = reinterpret_cast<const u32x4*>(ws + 1024)[kt * 64 + l];
        w2f[kt] = __builtin_bit_cast(bf16x8, q);
    }
    // L2 C-in: lane holds rows och = 4g..4g+3 -> per-lane bias quad
    float4 b4 = reinterpret_cast<const float4*>(b2)[g];
    const f32x4 bb = {b4.x, b4.y, b4.z, b4.w};
    const f32x4 z4 = {0.f, 0.f, 0.f, 0.f};
    __syncthreads();

    const int p0 = kblk * chunk;
    const int p1 = min(p0 + chunk, nper);
    const float* xb = xin + (size_t)b * nper * 3;
    const int STRIDE = (TPB / 64) * NT * 16; // 1024 points per block-iter

    // prefetched x for current iteration
    float cx[NT], cy[NT], cz[NT];
#pragma unroll
    for (int t = 0; t < NT; ++t) {
        int p = min(p0 + wv * (NT * 16) + t * 16 + lp, nper - 1);
        cx[t] = xb[p * 3 + 0]; cy[t] = xb[p * 3 + 1]; cz[t] = xb[p * 3 + 2];
    }

    for (int gb = p0 + wv * (NT * 16); gb < p1; gb += STRIDE) {
        // ---- issue next-iter x loads early (clamped, branchless) ----
        float nx[NT], ny[NT], nz[NT];
#pragma unroll
        for (int t = 0; t < NT; ++t) {
            int p = min(gb + STRIDE + t * 16 + lp, nper - 1);
            nx[t] = xb[p * 3 + 0]; ny[t] = xb[p * 3 + 1]; nz[t] = xb[p * 3 + 2];
        }

        int cell16[NT];
        bf16x8 bx[NT];
#pragma unroll
        for (int t = 0; t < NT; ++t) {
            cell16[t] = ((min(max((int)floorf(cx[t]), 0), 15) << 8) |
                         (min(max((int)floorf(cy[t]), 0), 15) << 4) |
                          min(max((int)floorf(cz[t]), 0), 15));
            bx[t] = mk_frag(g0 ? pkbf16(cx[t], cy[t]) : 0u,
                            g0 ? pkbf16(cz[t], 1.0f) : 0u);
        }

        f32x4 acc[NT];
#pragma unroll
        for (int t = 0; t < NT; ++t) acc[t] = bb;

#pragma unroll
        for (int kt = 0; kt < 8; ++kt) {
#pragma unroll
            for (int t = 0; t < NT; ++t) {
                f32x4 h0 = __builtin_amdgcn_mfma_f32_16x16x32_bf16(w1f[2*kt],   bx[t], z4, 0, 0, 0);
                f32x4 h1 = __builtin_amdgcn_mfma_f32_16x16x32_bf16(w1f[2*kt+1], bx[t], z4, 0, 0, 0);
                u32x4 ua;
                ua[0] = pkbf16(fmaxf(h0[0],0.f), fmaxf(h0[1],0.f));
                ua[1] = pkbf16(fmaxf(h0[2],0.f), fmaxf(h0[3],0.f));
                ua[2] = pkbf16(fmaxf(h1[0],0.f), fmaxf(h1[1],0.f));
                ua[3] = pkbf16(fmaxf(h1[2],0.f), fmaxf(h1[3],0.f));
                // operand-swapped L2: D[och][pt], b2 pre-folded via C-in
                acc[t] = __builtin_amdgcn_mfma_f32_16x16x32_bf16(
                             w2f[kt], __builtin_bit_cast(bf16x8, ua), acc[t], 0, 0, 0);
            }
        }

        // ---- epilogue per tile: all in-lane, 2 casmax, no shuffles ----
#pragma unroll
        for (int t = 0; t < NT; ++t) {
            if (gb + t * 16 + lp < p1) {
                unsigned w01 = mpk(pkbf16(acc[t][0], acc[t][1]));  // ch 4g, 4g+1
                unsigned w23 = mpk(pkbf16(acc[t][2], acc[t][3]));  // ch 4g+2, 4g+3
                unsigned* base = &cm[cell16[t] * 8 + 2 * g];
                casmax(base,     w01);
                casmax(base + 1, w23);
            }
        }

#pragma unroll
        for (int t = 0; t < NT; ++t) { cx[t] = nx[t]; cy[t] = ny[t]; cz[t] = nz[t]; }
    }
    __syncthreads();

    // flush slab (flat copy; layout preserved)
    unsigned* dst = slabs + (size_t)(kblk * BATCH + b) * SLAB_WORDS;
    uint4* d4 = reinterpret_cast<uint4*>(dst);
    const uint4* s4 = reinterpret_cast<const uint4*>(cm);
    for (int i = tid; i < SLAB_WORDS / 4; i += TPB) d4[i] = s4[i];
}

// ---------------------------------------------------------------------------
// reduce K slabs -> out interior. thread = (b, cell); reads 8 contiguous
// words per slab (2x uint4), writes 16 channels.
__global__ __launch_bounds__(256)
void k_reduce3(const unsigned* __restrict__ slabs, float* __restrict__ out, int K) {
    int t = blockIdx.x * 256 + threadIdx.x;
    if (t >= BATCH * NCELL) return;
    int cell = t & (NCELL - 1), b = t >> 12;

    unsigned m[8];
#pragma unroll
    for (int i = 0; i < 8; ++i) m[i] = SENTPK;

    for (int k = 0; k < K; ++k) {
        const uint4* s = reinterpret_cast<const uint4*>(
            slabs + (size_t)(k * BATCH + b) * SLAB_WORDS + (size_t)cell * 8);
        uint4 a = s[0], c = s[1];
        m[0] = pmax(m[0], a.x); m[1] = pmax(m[1], a.y);
        m[2] = pmax(m[2], a.z); m[3] = pmax(m[3], a.w);
        m[4] = pmax(m[4], c.x); m[5] = pmax(m[5], c.y);
        m[6] = pmax(m[6], c.z); m[7] = pmax(m[7], c.w);
    }

    int ix = cell >> 8, iy = (cell >> 4) & 15, iz = cell & 15;
    size_t obase = ((size_t)b * ODIM) * PADV + ((ix * PADW + iy) * PADW + iz);
#pragma unroll
    for (int op = 0; op < 8; ++op) {
        unsigned lo = m[op] & 0xFFFFu, hi = m[op] >> 16;
        out[obase + (size_t)(2 * op)     * PADV] = (lo == SENT16) ? 0.0f : unmap16(lo);
        out[obase + (size_t)(2 * op + 1) * PADV] = (hi == SENT16) ? 0.0f : unmap16(hi);
    }
}

// ===========================================================================
// Fallback (round-1): direct global atomics. Used only if ws too small.
__global__ void k_init(unsigned* __restrict__ out, int total) {
    int i = blockIdx.x * blockDim.x + threadIdx.x;
    if (i >= total) return;
    int r = i % PADV;
    int z = r % PADW, y = (r / PADW) % PADW, x = r / (PADW * PADW);
    out[i] = (x < GRID16 && y < GRID16 && z < GRID16) ? 0xFF800000u : 0u;
}
__device__ __forceinline__ void atomicMaxFloat(float* addr, float v) {
    if (v >= 0.0f) atomicMax(reinterpret_cast<int*>(addr), __float_as_int(v));
    else           atomicMin(reinterpret_cast<unsigned*>(addr), __float_as_uint(v));
}
__global__ __launch_bounds__(256)
void k_scatter_glb(const float* __restrict__ xin,
                   const float* __restrict__ W1, const float* __restrict__ b1,
                   const float* __restrict__ W2, const float* __restrict__ b2,
                   float* __restrict__ out, int npts, int nper) {
    int p = blockIdx.x * 256 + threadIdx.x;
    if (p >= npts) return;
    float x0 = xin[p*3+0], x1 = xin[p*3+1], x2 = xin[p*3+2];
    float acc[ODIM];
#pragma unroll
    for (int o = 0; o < ODIM; ++o) acc[o] = b2[o];
#pragma unroll 2
    for (int c = 0; c < CDIM; ++c) {
        float h = fmaf(W1[c*3+0], x0, fmaf(W1[c*3+1], x1, fmaf(W1[c*3+2], x2, b1[c])));
        h = fmaxf(h, 0.0f);
#pragma unroll
        for (int o = 0; o < ODIM; ++o) acc[o] = fmaf(W2[o*CDIM+c], h, acc[o]);
    }
    int ix = min(max((int)floorf(x0), 0), GRID16-1);
    int iy = min(max((int)floorf(x1), 0), GRID16-1);
    int iz = min(max((int)floorf(x2), 0), GRID16-1);
    int b = p / nper;
    size_t base = ((((size_t)b*ODIM)*PADW + ix)*PADW + iy)*PADW + iz;
#pragma unroll
    for (int o = 0; o < ODIM; ++o)
        atomicMaxFloat(out + base + (size_t)o*PADV, acc[o]);
}
__global__ void k_final(unsigned* __restrict__ out, int total) {
    int i = blockIdx.x * blockDim.x + threadIdx.x;
    if (i >= total) return;
    if (out[i] == 0xFF800000u) out[i] = 0u;
}

// ===========================================================================
extern "C" void kernel_launch(void* const* d_in, const int* in_sizes, int n_in,
                              void* d_out, int out_size, void* d_ws, size_t ws_size,
                              hipStream_t stream) {
    const float* x  = (const float*)d_in[0];
    const float* W1 = (const float*)d_in[1];
    const float* b1 = (const float*)d_in[2];
    const float* W2 = (const float*)d_in[3];
    const float* b2 = (const float*)d_in[4];
    float* out = (float*)d_out;

    int npts = in_sizes[0] / 3;          // B*N
    int nper = npts / BATCH;             // N

    size_t ws_words = ws_size / 4;
    int Km = 0;
    if (ws_words > HDR_WORDS) {
        size_t avail = (ws_words - HDR_WORDS) / ((size_t)BATCH * SLAB_WORDS);
        Km = (int)min((size_t)MAXK, avail);
    }

    if (Km >= 1) {
        unsigned* ws = (unsigned*)d_ws;
        k_pack2<<<1, 512, 0, stream>>>(W1, b1, W2, ws);
        (void)hipMemsetAsync(d_out, 0, (size_t)out_size * sizeof(float), stream);

        unsigned* slabs = ws + HDR_WORDS;
        int chunk = (nper + Km - 1) / Km;
        dim3 grid(Km, 1, BATCH);
        k_scatter_mfma<<<grid, TPB, 0, stream>>>(x, ws, b2, slabs, nper, chunk);

        int rt = BATCH * NCELL;
        k_reduce3<<<(rt + 255) / 256, 256, 0, stream>>>(slabs, out, Km);
    } else {
        int total = out_size;
        k_init<<<(total + 255) / 256, 256, 0, stream>>>((unsigned*)out, total);
        int blocks = (npts + 255) / 256;
        k_scatter_glb<<<blocks, 256, 0, stream>>>(x, W1, b1, W2, b2, out, npts, nper);
        k_final<<<(total + 255) / 256, 256, 0, stream>>>((unsigned*)out, total);
    }
}

// Round 15
// 65.861 us; speedup vs baseline: 1.2426x; 1.2426x over previous
//
#include <hip/hip_runtime.h>
#include <hip/hip_bf16.h>

// Problem constants (match reference)
#define BATCH   8
#define CDIM    256
#define ODIM    16
#define GRID16  16
#define NCELL   4096            // 16*16*16
#define PADW    17
#define PADV    (PADW*PADW*PADW)
#define MAXK    32              // point chunks per batch (256 blocks total)
#define SENT16  0x007Fu         // mapped bf16 -inf
#define SENTPK  0x007F007Fu
#define TPB     768             // 12 waves = 3/SIMD (TLP ceiling: R14 proved 4/SIMD forces 64/64 split)
#define NT      4               // M-tiles (16 pts each) per wave-iteration

// ws layout (u32 words):
//   [0, 1024)      : W1b1 packed float4 per c  (w1x,w1y,w1z,b1)
//   [1024, 3072)   : W2 bf16 MFMA A-fragments, uint4 per (kt*64+lane)
//   [4096, ...)    : Km * BATCH slabs of 4096*8 packed-bf16-pair u32
//                    word index = cell*8 + op   (op = channel pair 0..7)
#define HDR_WORDS   4096
#define SLAB_WORDS  (8 * 4096)   // 32768 u32 = 128 KiB

typedef __attribute__((ext_vector_type(8))) short bf16x8;
typedef __attribute__((ext_vector_type(4))) float f32x4;
typedef __attribute__((ext_vector_type(4))) unsigned u32x4;
typedef unsigned long long u64;

// ---------------------------------------------------------------------------
__device__ __forceinline__ float unmap16(unsigned m) {
    unsigned r = (m & 0x8000u) ? (m ^ 0x8000u) : (~m & 0xFFFFu);
    return __uint_as_float(r << 16);
}
// packed pair map: per 16-bit field, r ^= (sign ? 0xFFFF : 0x8000)
__device__ __forceinline__ unsigned mpk(unsigned w) {
    return w ^ (0x80008000u | (((w >> 15) & 0x00010001u) * 0x7FFFu));
}
// two fp32 -> packed bf16 pair (lo = first): single HW instruction (T12)
__device__ __forceinline__ unsigned pkbf16(float lo, float hi) {
    unsigned r;
    asm("v_cvt_pk_bf16_f32 %0, %1, %2" : "=v"(r) : "v"(lo), "v"(hi));
    return r;
}
// packed-pair unsigned max per 16-bit field
__device__ __forceinline__ unsigned pmax(unsigned a, unsigned b) {
    unsigned hi = max(a >> 16, b >> 16);
    unsigned lo = max(a & 0xFFFFu, b & 0xFFFFu);
    return (hi << 16) | lo;
}
// 4x bf16-mapped fields in a u64
__device__ __forceinline__ u64 pmax64(u64 a, u64 b) {
    unsigned lo = pmax((unsigned)a, (unsigned)b);
    unsigned hi = pmax((unsigned)(a >> 32), (unsigned)(b >> 32));
    return ((u64)hi << 32) | lo;
}

// ---------------------------------------------------------------------------
__global__ void k_pack2(const float* __restrict__ W1, const float* __restrict__ b1,
                        const float* __restrict__ W2, unsigned* __restrict__ ws) {
    int t = threadIdx.x;                    // 512 threads
    float* w1p = reinterpret_cast<float*>(ws);
    if (t < 256) {
        float4 v;
        v.x = W1[t * 3 + 0];
        v.y = W1[t * 3 + 1];
        v.z = W1[t * 3 + 2];
        v.w = b1[t];
        reinterpret_cast<float4*>(w1p)[t] = v;
    }
    // W2 A fragments, k-map c(kt,j,g) = kt*32 + (j>>2)*16 + 4g + (j&3)
    int kt = t >> 6, l = t & 63;
    int g = (l >> 4), o = l & 15;
    const float* wr = W2 + o * CDIM + kt * 32 + 4 * g;   // base
    uint4 q;
    q.x = pkbf16(wr[0],  wr[1]);
    q.y = pkbf16(wr[2],  wr[3]);
    q.z = pkbf16(wr[16], wr[17]);
    q.w = pkbf16(wr[18], wr[19]);
    reinterpret_cast<uint4*>(ws + 1024)[t] = q;
}

// ---------------------------------------------------------------------------
// 64-bit CAS max: one DS atomic covers 4 bf16-mapped fields (2 words).
// Halves the LDS-atomic op count vs 2x 32-bit CAS -- R15's single lever.
__device__ __forceinline__ void casmax64(u64* addr, u64 wv) {
    u64 cur = *addr;
    while (true) {
        u64 nv = pmax64(cur, wv);
        if (nv == cur) return;
        u64 prev = atomicCAS(addr, cur, nv);
        if (prev == cur) return;
        cur = prev;
    }
}

__device__ __forceinline__ bf16x8 mk_frag(unsigned w0, unsigned w1) {
    u32x4 u = {w0, w1, 0u, 0u};
    return __builtin_bit_cast(bf16x8, u);
}

// ---------------------------------------------------------------------------
// MFMA scatter: block (k, b). 12 waves (3/SIMD); NT=4 16-point M-tiles per
// wave-iteration. Both layers on MFMA, fragments in VGPRs.
//   L1: h[ch16][pt16]  = W1(A) * x(B)            [K=4 of 32 used]
//   L2: D[och16][pt16] = W2(A) * h(B) + b2(C-in) [operand-swapped]
// Post-R14 accounting: the wall is the LDS-atomic pipe (~16 DS ops/pt).
// This round: u64 CAS -> 8 DS ops/pt. u64[cell*4+g] has the same byte
// layout as word-pair [cell*8+2g, +1], so init/flush/reduce are unchanged.
__global__ __launch_bounds__(TPB, 1)
void k_scatter_mfma(const float* __restrict__ xin,
                    const unsigned* __restrict__ ws,
                    const float* __restrict__ b2,
                    unsigned* __restrict__ slabs,
                    int nper, int chunk) {
    __shared__ u64 cm64[SLAB_WORDS / 2];     // 128 KiB, 8B-aligned
    unsigned* cm = reinterpret_cast<unsigned*>(cm64);
    const int kblk = blockIdx.x, b = blockIdx.z;
    const int tid = threadIdx.x;
    const int l = tid & 63, wv = tid >> 6;   // lane, wave (0..11)
    const int g = l >> 4;                    // lane group 0..3
    const bool g0 = (g == 0);
    const int lp = l & 15;                   // point slot within tile

    {   // vectorized sentinel init: 8192 uint4
        u32x4 s = {SENTPK, SENTPK, SENTPK, SENTPK};
        u32x4* cm4 = reinterpret_cast<u32x4*>(cm);
        for (int i = tid; i < SLAB_WORDS / 4; i += TPB) cm4[i] = s;
    }

    // ---- W1 A-fragments (16 channel groups) into registers ----
    bf16x8 w1f[16];
    {
        const float4* w1p = reinterpret_cast<const float4*>(ws);
#pragma unroll
        for (int cg = 0; cg < 16; ++cg) {
            float4 w = w1p[cg * 16 + lp];
            unsigned a0 = g0 ? pkbf16(w.x, w.y) : 0u;
            unsigned a1 = g0 ? pkbf16(w.z, w.w) : 0u;
            w1f[cg] = mk_frag(a0, a1);
        }
    }
    // ---- W2 A-fragments into registers ----
    bf16x8 w2f[8];
#pragma unroll
    for (int kt = 0; kt < 8; ++kt) {
        u32x4 q = reinterpret_cast<const u32x4*>(ws + 1024)[kt * 64 + l];
        w2f[kt] = __builtin_bit_cast(bf16x8, q);
    }
    // L2 C-in: lane holds rows och = 4g..4g+3 -> per-lane bias quad
    float4 b4 = reinterpret_cast<const float4*>(b2)[g];
    const f32x4 bb = {b4.x, b4.y, b4.z, b4.w};
    const f32x4 z4 = {0.f, 0.f, 0.f, 0.f};
    __syncthreads();

    const int p0 = kblk * chunk;
    const int p1 = min(p0 + chunk, nper);
    const float* xb = xin + (size_t)b * nper * 3;
    const int STRIDE = (TPB / 64) * NT * 16; // 768 points per block-iter

    // prefetched x for current iteration
    float cx[NT], cy[NT], cz[NT];
#pragma unroll
    for (int t = 0; t < NT; ++t) {
        int p = min(p0 + wv * (NT * 16) + t * 16 + lp, nper - 1);
        cx[t] = xb[p * 3 + 0]; cy[t] = xb[p * 3 + 1]; cz[t] = xb[p * 3 + 2];
    }

    for (int gb = p0 + wv * (NT * 16); gb < p1; gb += STRIDE) {
        // ---- issue next-iter x loads early (clamped, branchless) ----
        float nx[NT], ny[NT], nz[NT];
#pragma unroll
        for (int t = 0; t < NT; ++t) {
            int p = min(gb + STRIDE + t * 16 + lp, nper - 1);
            nx[t] = xb[p * 3 + 0]; ny[t] = xb[p * 3 + 1]; nz[t] = xb[p * 3 + 2];
        }

        int cell16[NT];
        bf16x8 bx[NT];
#pragma unroll
        for (int t = 0; t < NT; ++t) {
            cell16[t] = ((min(max((int)floorf(cx[t]), 0), 15) << 8) |
                         (min(max((int)floorf(cy[t]), 0), 15) << 4) |
                          min(max((int)floorf(cz[t]), 0), 15));
            bx[t] = mk_frag(g0 ? pkbf16(cx[t], cy[t]) : 0u,
                            g0 ? pkbf16(cz[t], 1.0f) : 0u);
        }

        f32x4 acc[NT];
#pragma unroll
        for (int t = 0; t < NT; ++t) acc[t] = bb;

#pragma unroll
        for (int kt = 0; kt < 8; ++kt) {
#pragma unroll
            for (int t = 0; t < NT; ++t) {
                f32x4 h0 = __builtin_amdgcn_mfma_f32_16x16x32_bf16(w1f[2*kt],   bx[t], z4, 0, 0, 0);
                f32x4 h1 = __builtin_amdgcn_mfma_f32_16x16x32_bf16(w1f[2*kt+1], bx[t], z4, 0, 0, 0);
                u32x4 ua;
                ua[0] = pkbf16(fmaxf(h0[0],0.f), fmaxf(h0[1],0.f));
                ua[1] = pkbf16(fmaxf(h0[2],0.f), fmaxf(h0[3],0.f));
                ua[2] = pkbf16(fmaxf(h1[0],0.f), fmaxf(h1[1],0.f));
                ua[3] = pkbf16(fmaxf(h1[2],0.f), fmaxf(h1[3],0.f));
                // operand-swapped L2: D[och][pt], b2 pre-folded via C-in
                acc[t] = __builtin_amdgcn_mfma_f32_16x16x32_bf16(
                             w2f[kt], __builtin_bit_cast(bf16x8, ua), acc[t], 0, 0, 0);
            }
        }

        // ---- epilogue per tile: in-lane, ONE u64 casmax per lane ----
#pragma unroll
        for (int t = 0; t < NT; ++t) {
            if (gb + t * 16 + lp < p1) {
                unsigned w01 = mpk(pkbf16(acc[t][0], acc[t][1]));  // ch 4g, 4g+1
                unsigned w23 = mpk(pkbf16(acc[t][2], acc[t][3]));  // ch 4g+2, 4g+3
                u64 wq = ((u64)w23 << 32) | w01;
                casmax64(&cm64[cell16[t] * 4 + g], wq);
            }
        }

#pragma unroll
        for (int t = 0; t < NT; ++t) { cx[t] = nx[t]; cy[t] = ny[t]; cz[t] = nz[t]; }
    }
    __syncthreads();

    // flush slab (flat copy; layout preserved)
    unsigned* dst = slabs + (size_t)(kblk * BATCH + b) * SLAB_WORDS;
    uint4* d4 = reinterpret_cast<uint4*>(dst);
    const uint4* s4 = reinterpret_cast<const uint4*>(cm);
    for (int i = tid; i < SLAB_WORDS / 4; i += TPB) d4[i] = s4[i];
}

// ---------------------------------------------------------------------------
// reduce K slabs -> out interior. thread = (b, cell); reads 8 contiguous
// words per slab (2x uint4), writes 16 channels.
__global__ __launch_bounds__(256)
void k_reduce3(const unsigned* __restrict__ slabs, float* __restrict__ out, int K) {
    int t = blockIdx.x * 256 + threadIdx.x;
    if (t >= BATCH * NCELL) return;
    int cell = t & (NCELL - 1), b = t >> 12;

    unsigned m[8];
#pragma unroll
    for (int i = 0; i < 8; ++i) m[i] = SENTPK;

    for (int k = 0; k < K; ++k) {
        const uint4* s = reinterpret_cast<const uint4*>(
            slabs + (size_t)(k * BATCH + b) * SLAB_WORDS + (size_t)cell * 8);
        uint4 a = s[0], c = s[1];
        m[0] = pmax(m[0], a.x); m[1] = pmax(m[1], a.y);
        m[2] = pmax(m[2], a.z); m[3] = pmax(m[3], a.w);
        m[4] = pmax(m[4], c.x); m[5] = pmax(m[5], c.y);
        m[6] = pmax(m[6], c.z); m[7] = pmax(m[7], c.w);
    }

    int ix = cell >> 8, iy = (cell >> 4) & 15, iz = cell & 15;
    size_t obase = ((size_t)b * ODIM) * PADV + ((ix * PADW + iy) * PADW + iz);
#pragma unroll
    for (int op = 0; op < 8; ++op) {
        unsigned lo = m[op] & 0xFFFFu, hi = m[op] >> 16;
        out[obase + (size_t)(2 * op)     * PADV] = (lo == SENT16) ? 0.0f : unmap16(lo);
        out[obase + (size_t)(2 * op + 1) * PADV] = (hi == SENT16) ? 0.0f : unmap16(hi);
    }
}

// ===========================================================================
// Fallback (round-1): direct global atomics. Used only if ws too small.
__global__ void k_init(unsigned* __restrict__ out, int total) {
    int i = blockIdx.x * blockDim.x + threadIdx.x;
    if (i >= total) return;
    int r = i % PADV;
    int z = r % PADW, y = (r / PADW) % PADW, x = r / (PADW * PADW);
    out[i] = (x < GRID16 && y < GRID16 && z < GRID16) ? 0xFF800000u : 0u;
}
__device__ __forceinline__ void atomicMaxFloat(float* addr, float v) {
    if (v >= 0.0f) atomicMax(reinterpret_cast<int*>(addr), __float_as_int(v));
    else           atomicMin(reinterpret_cast<unsigned*>(addr), __float_as_uint(v));
}
__global__ __launch_bounds__(256)
void k_scatter_glb(const float* __restrict__ xin,
                   const float* __restrict__ W1, const float* __restrict__ b1,
                   const float* __restrict__ W2, const float* __restrict__ b2,
                   float* __restrict__ out, int npts, int nper) {
    int p = blockIdx.x * 256 + threadIdx.x;
    if (p >= npts) return;
    float x0 = xin[p*3+0], x1 = xin[p*3+1], x2 = xin[p*3+2];
    float acc[ODIM];
#pragma unroll
    for (int o = 0; o < ODIM; ++o) acc[o] = b2[o];
#pragma unroll 2
    for (int c = 0; c < CDIM; ++c) {
        float h = fmaf(W1[c*3+0], x0, fmaf(W1[c*3+1], x1, fmaf(W1[c*3+2], x2, b1[c])));
        h = fmaxf(h, 0.0f);
#pragma unroll
        for (int o = 0; o < ODIM; ++o) acc[o] = fmaf(W2[o*CDIM+c], h, acc[o]);
    }
    int ix = min(max((int)floorf(x0), 0), GRID16-1);
    int iy = min(max((int)floorf(x1), 0), GRID16-1);
    int iz = min(max((int)floorf(x2), 0), GRID16-1);
    int b = p / nper;
    size_t base = ((((size_t)b*ODIM)*PADW + ix)*PADW + iy)*PADW + iz;
#pragma unroll
    for (int o = 0; o < ODIM; ++o)
        atomicMaxFloat(out + base + (size_t)o*PADV, acc[o]);
}
__global__ void k_final(unsigned* __restrict__ out, int total) {
    int i = blockIdx.x * blockDim.x + threadIdx.x;
    if (i >= total) return;
    if (out[i] == 0xFF800000u) out[i] = 0u;
}

// ===========================================================================
extern "C" void kernel_launch(void* const* d_in, const int* in_sizes, int n_in,
                              void* d_out, int out_size, void* d_ws, size_t ws_size,
                              hipStream_t stream) {
    const float* x  = (const float*)d_in[0];
    const float* W1 = (const float*)d_in[1];
    const float* b1 = (const float*)d_in[2];
    const float* W2 = (const float*)d_in[3];
    const float* b2 = (const float*)d_in[4];
    float* out = (float*)d_out;

    int npts = in_sizes[0] / 3;          // B*N
    int nper = npts / BATCH;             // N

    size_t ws_words = ws_size / 4;
    int Km = 0;
    if (ws_words > HDR_WORDS) {
        size_t avail = (ws_words - HDR_WORDS) / ((size_t)BATCH * SLAB_WORDS);
        Km = (int)min((size_t)MAXK, avail);
    }

    if (Km >= 1) {
        unsigned* ws = (unsigned*)d_ws;
        k_pack2<<<1, 512, 0, stream>>>(W1, b1, W2, ws);
        (void)hipMemsetAsync(d_out, 0, (size_t)out_size * sizeof(float), stream);

        unsigned* slabs = ws + HDR_WORDS;
        int chunk = (nper + Km - 1) / Km;
        dim3 grid(Km, 1, BATCH);
        k_scatter_mfma<<<grid, TPB, 0, stream>>>(x, ws, b2, slabs, nper, chunk);

        int rt = BATCH * NCELL;
        k_reduce3<<<(rt + 255) / 256, 256, 0, stream>>>(slabs, out, Km);
    } else {
        int total = out_size;
        k_init<<<(total + 255) / 256, 256, 0, stream>>>((unsigned*)out, total);
        int blocks = (npts + 255) / 256;
        k_scatter_glb<<<blocks, 256, 0, stream>>>(x, W1, b1, W2, b2, out, npts, nper);
        k_final<<<(total + 255) / 256, 256, 0, stream>>>((unsigned*)out, total);
    }
}